// Round 5
// baseline (2493.160 us; speedup 1.0000x reference)
//
#include <hip/hip_runtime.h>
#include <cstdint>
#include <cstddef>

#define HWDIM 56
#define NBATCH 8
#define NHEADS 16
#define HDIM 32
#define CDIM 512
#define QKV_N 1536
#define KSZ 7
#define RAD 3
#define NPIX (NBATCH*HWDIM*HWDIM)          // 25088
#define SCALE 0.17677669529663687f         // 32^-0.5

typedef unsigned short u16;
typedef __bf16 bf16x8 __attribute__((ext_vector_type(8)));
typedef float  f32x4  __attribute__((ext_vector_type(4)));
typedef _Float16 h2 __attribute__((ext_vector_type(2)));
typedef _Float16 h8 __attribute__((ext_vector_type(8)));

// ---- bf16 helpers (RNE) ----
__device__ __forceinline__ u16 f2bf(float x) {
    union { float f; unsigned u; } v; v.f = x;
    unsigned r = v.u + 0x7fff + ((v.u >> 16) & 1);
    return (u16)(r >> 16);
}
__device__ __forceinline__ float bf2f(u16 h) {
    union { float f; unsigned u; } v; v.u = ((unsigned)h) << 16; return v.f;
}

// async global->LDS, 16B per lane (lane-linear LDS dest per m104/m108)
__device__ __forceinline__ void gload16(const void* g, void* l) {
    __builtin_amdgcn_global_load_lds(
        (const __attribute__((address_space(1))) unsigned int*)g,
        (__attribute__((address_space(3))) unsigned int*)l, 16, 0, 0);
}

// ---------------------------------------------------------------------------
// prep: fp32 -> (hi, lo) bf16 split, elementwise (vectorized x4)
// ---------------------------------------------------------------------------
__global__ __launch_bounds__(256)
void split_f32(const float* __restrict__ in, u16* __restrict__ hi,
               u16* __restrict__ lo, int n4)
{
    int i = blockIdx.x * 256 + threadIdx.x;
    if (i >= n4) return;
    float4 v = ((const float4*)in)[i];
    ushort4 h, l;
    h.x = f2bf(v.x); l.x = f2bf(v.x - bf2f(h.x));
    h.y = f2bf(v.y); l.y = f2bf(v.y - bf2f(h.y));
    h.z = f2bf(v.z); l.z = f2bf(v.z - bf2f(h.z));
    h.w = f2bf(v.w); l.w = f2bf(v.w - bf2f(h.w));
    ((ushort4*)hi)[i] = h;
    ((ushort4*)lo)[i] = l;
}

// ---------------------------------------------------------------------------
// prep: W[K][N] fp32 -> Wt[N][K] (hi, lo) bf16
// ---------------------------------------------------------------------------
__global__ __launch_bounds__(256)
void transpose_split(const float* __restrict__ w, u16* __restrict__ th,
                     u16* __restrict__ tl, int K, int N)
{
    int idx = blockIdx.x * 256 + threadIdx.x;
    if (idx >= K * N) return;
    int n = idx / K, k = idx - n * K;
    float v = w[(size_t)k * N + n];
    u16 h = f2bf(v);
    th[idx] = h;
    tl[idx] = f2bf(v - bf2f(h));
}

// ---------------------------------------------------------------------------
// split-bf16 MFMA GEMM + bias (unchanged; passed r3 @4.9e-4)
// ---------------------------------------------------------------------------
__global__ __launch_bounds__(256, 2)
void gemm_split_bf16(const u16* __restrict__ Ah, const u16* __restrict__ Al,
                     const u16* __restrict__ Bh, const u16* __restrict__ Bl,
                     const float* __restrict__ bias, float* __restrict__ C,
                     int M, int N, int K)
{
    __shared__ __bf16 sAh[128 * 32], sAl[128 * 32];
    __shared__ __bf16 sBh[128 * 32], sBl[128 * 32];

    const int nbx  = N >> 7;
    const int bx   = blockIdx.x % nbx;
    const int by   = blockIdx.x / nbx;
    const int m0   = by << 7;
    const int n0   = bx << 7;
    const int tid  = threadIdx.x;
    const int lane = tid & 63;
    const int wid  = tid >> 6;
    const int wr   = wid >> 1;
    const int wc   = wid & 1;

    f32x4 acc[4][4];
#pragma unroll
    for (int m = 0; m < 4; ++m)
#pragma unroll
        for (int n = 0; n < 4; ++n)
#pragma unroll
            for (int j = 0; j < 4; ++j) acc[m][n][j] = 0.f;

    int a_off[4], b_off[4];
#pragma unroll
    for (int m = 0; m < 4; ++m) {
        int row = wr * 64 + m * 16 + (lane & 15);
        int kb  = lane >> 4;
        a_off[m] = row * 32 + (kb ^ ((row >> 1) & 3)) * 8;
    }
#pragma unroll
    for (int n = 0; n < 4; ++n) {
        int row = wc * 64 + n * 16 + (lane & 15);
        int kb  = lane >> 4;
        b_off[n] = row * 32 + (kb ^ ((row >> 1) & 3)) * 8;
    }

    int s_row[2], s_kbg[2], s_lds[2];
#pragma unroll
    for (int it = 0; it < 2; ++it) {
        int s = it * 256 + tid;
        int row = s >> 2, kbs = s & 3;
        s_row[it] = row;
        s_kbg[it] = kbs ^ ((row >> 1) & 3);
        s_lds[it] = s * 8;
    }

    for (int kt = 0; kt < K; kt += 32) {
#pragma unroll
        for (int it = 0; it < 2; ++it) {
            const size_t ga = (size_t)(m0 + s_row[it]) * K + kt + s_kbg[it] * 8;
            const size_t gb = (size_t)(n0 + s_row[it]) * K + kt + s_kbg[it] * 8;
            gload16(Ah + ga, (void*)(sAh + s_lds[it]));
            gload16(Al + ga, (void*)(sAl + s_lds[it]));
            gload16(Bh + gb, (void*)(sBh + s_lds[it]));
            gload16(Bl + gb, (void*)(sBl + s_lds[it]));
        }
        __syncthreads();

        bf16x8 ah[4], al[4], bh[4], bl[4];
#pragma unroll
        for (int m = 0; m < 4; ++m) {
            ah[m] = *(const bf16x8*)(sAh + a_off[m]);
            al[m] = *(const bf16x8*)(sAl + a_off[m]);
        }
#pragma unroll
        for (int n = 0; n < 4; ++n) {
            bh[n] = *(const bf16x8*)(sBh + b_off[n]);
            bl[n] = *(const bf16x8*)(sBl + b_off[n]);
        }
#pragma unroll
        for (int m = 0; m < 4; ++m)
#pragma unroll
            for (int n = 0; n < 4; ++n) {
                acc[m][n] = __builtin_amdgcn_mfma_f32_16x16x32_bf16(al[m], bh[n], acc[m][n], 0, 0, 0);
                acc[m][n] = __builtin_amdgcn_mfma_f32_16x16x32_bf16(ah[m], bl[n], acc[m][n], 0, 0, 0);
                acc[m][n] = __builtin_amdgcn_mfma_f32_16x16x32_bf16(ah[m], bh[n], acc[m][n], 0, 0, 0);
            }
        __syncthreads();
    }

#pragma unroll
    for (int m = 0; m < 4; ++m) {
        const int rbase = m0 + wr * 64 + m * 16 + (lane >> 4) * 4;
#pragma unroll
        for (int n = 0; n < 4; ++n) {
            const int col = n0 + wc * 64 + n * 16 + (lane & 15);
            const float bv = bias[col];
#pragma unroll
            for (int j = 0; j < 4; ++j)
                C[(size_t)(rbase + j) * N + col] = acc[m][n][j] + bv;
        }
    }
}

// ---------------------------------------------------------------------------
// NATTEN 7x7, v2b: K/V staged in LDS as fp16 (30,976 B -> 4 blocks/CU),
// QK^T via v_dot2_f32_f16, PV via mixed fma. `active` guard RESTORED:
// clamped edge threads (h/w >= 56) must not compute (their bh_base goes
// negative -> OOB rpb row -> wrong logits) nor race-write the clamped pixel.
// ---------------------------------------------------------------------------
__global__ __launch_bounds__(256, 4)
void natten2d(const float* __restrict__ qkv, const float* __restrict__ rpb,
              u16* __restrict__ oh, u16* __restrict__ ol)
{
    __shared__ _Float16 tile[484 * 32];   // 30,976 B; [pix][chunk^((pix>>1)&3)]

    const int tix  = blockIdx.x & 3;
    const int tiy  = blockIdx.x >> 2;
    const int head = blockIdx.y;
    const int b    = blockIdx.z;
    const int r0   = tiy * 16;
    const int c0   = tix * 16;
    const int bh0  = min(max(r0 - RAD, 0), HWDIM - 22);
    const int cw0  = min(max(c0 - RAD, 0), HWDIM - 22);

    const int tid = threadIdx.x;
    const int ph  = tid >> 4;
    const int pw  = tid & 15;
    const int h   = r0 + ph;
    const int w   = c0 + pw;
    const bool active = (h < HWDIM) && (w < HWDIM);
    const int hc = min(h, HWDIM - 1);
    const int wc = min(w, HWDIM - 1);
    const size_t pixg = (size_t)(b * HWDIM + hc) * HWDIM + wc;

    // ---- load q, scale, convert to fp16 pairs ----
    h2 q2[16];
    {
        const float* qp = qkv + pixg * QKV_N + head * HDIM;
#pragma unroll
        for (int d4 = 0; d4 < 8; ++d4) {
            float4 v = *(const float4*)(qp + d4 * 4);
            h2 t0, t1;
            t0[0] = (_Float16)(v.x * SCALE); t0[1] = (_Float16)(v.y * SCALE);
            t1[0] = (_Float16)(v.z * SCALE); t1[1] = (_Float16)(v.w * SCALE);
            q2[d4 * 2]     = t0;
            q2[d4 * 2 + 1] = t1;
        }
    }

    const int sh      = min(max(h - RAD, 0), HWDIM - KSZ);
    const int sw      = min(max(w - RAD, 0), HWDIM - KSZ);
    const int lh0     = sh - bh0;
    const int lw0     = sw - cw0;
    const int bh_base = sh + (KSZ - 1) - h;   // valid (0..6) only when active
    const int bw_base = sw + (KSZ - 1) - w;

    // ---- stage K into LDS (fp32 -> fp16), all threads ----
    for (int i = tid; i < 484 * 4; i += 256) {
        const int pix = i >> 2;
        const int c   = i & 3;
        const int row = pix / 22;
        const int col = pix - row * 22;
        const float* src = qkv +
            ((size_t)((b * HWDIM + bh0 + row) * HWDIM + cw0 + col)) * QKV_N
            + CDIM + head * HDIM + c * 8;
        float4 v0 = *(const float4*)src;
        float4 v1 = *(const float4*)(src + 4);
        h8 hv;
        hv[0] = (_Float16)v0.x; hv[1] = (_Float16)v0.y;
        hv[2] = (_Float16)v0.z; hv[3] = (_Float16)v0.w;
        hv[4] = (_Float16)v1.x; hv[5] = (_Float16)v1.y;
        hv[6] = (_Float16)v1.z; hv[7] = (_Float16)v1.w;
        *(h8*)&tile[pix * 32 + ((c ^ ((pix >> 1) & 3)) << 3)] = hv;
    }
    __syncthreads();

    // ---- QK^T: 49 logits per pixel (active threads only) ----
    float logit[49];
    float mmax = -1e30f;
    if (active) {
#pragma unroll
        for (int a = 0; a < KSZ; ++a) {
#pragma unroll
            for (int bb = 0; bb < KSZ; ++bb) {
                const int pix = (lh0 + a) * 22 + (lw0 + bb);
                const int sx  = (pix >> 1) & 3;
                const _Float16* kb = &tile[pix * 32];
                float s = 0.f;
#pragma unroll
                for (int c = 0; c < 4; ++c) {
                    h8 kv = *(const h8*)(kb + ((c ^ sx) << 3));
                    h2 p0 = __builtin_shufflevector(kv, kv, 0, 1);
                    h2 p1 = __builtin_shufflevector(kv, kv, 2, 3);
                    h2 p2 = __builtin_shufflevector(kv, kv, 4, 5);
                    h2 p3 = __builtin_shufflevector(kv, kv, 6, 7);
                    s = __builtin_amdgcn_fdot2(q2[c * 4 + 0], p0, s, false);
                    s = __builtin_amdgcn_fdot2(q2[c * 4 + 1], p1, s, false);
                    s = __builtin_amdgcn_fdot2(q2[c * 4 + 2], p2, s, false);
                    s = __builtin_amdgcn_fdot2(q2[c * 4 + 3], p3, s, false);
                }
                s += rpb[head * 169 + (bh_base + a) * 13 + (bw_base + bb)];
                logit[a * KSZ + bb] = s;
                mmax = fmaxf(mmax, s);
            }
        }
    }
    __syncthreads();   // all K reads complete before V overwrites the buffer

    // ---- stage V into LDS (same buffer), all threads ----
    for (int i = tid; i < 484 * 4; i += 256) {
        const int pix = i >> 2;
        const int c   = i & 3;
        const int row = pix / 22;
        const int col = pix - row * 22;
        const float* src = qkv +
            ((size_t)((b * HWDIM + bh0 + row) * HWDIM + cw0 + col)) * QKV_N
            + 2 * CDIM + head * HDIM + c * 8;
        float4 v0 = *(const float4*)src;
        float4 v1 = *(const float4*)(src + 4);
        h8 hv;
        hv[0] = (_Float16)v0.x; hv[1] = (_Float16)v0.y;
        hv[2] = (_Float16)v0.z; hv[3] = (_Float16)v0.w;
        hv[4] = (_Float16)v1.x; hv[5] = (_Float16)v1.y;
        hv[6] = (_Float16)v1.z; hv[7] = (_Float16)v1.w;
        *(h8*)&tile[pix * 32 + ((c ^ ((pix >> 1) & 3)) << 3)] = hv;
    }
    __syncthreads();

    // ---- softmax + PV + store (active threads only) ----
    if (active) {
        float accv[32];
#pragma unroll
        for (int d = 0; d < 32; ++d) accv[d] = 0.f;
        float lsum = 0.f;
#pragma unroll
        for (int a = 0; a < KSZ; ++a) {
#pragma unroll
            for (int bb = 0; bb < KSZ; ++bb) {
                const float p = __expf(logit[a * KSZ + bb] - mmax);
                lsum += p;
                const int pix = (lh0 + a) * 22 + (lw0 + bb);
                const int sx  = (pix >> 1) & 3;
                const _Float16* vb = &tile[pix * 32];
#pragma unroll
                for (int c = 0; c < 4; ++c) {
                    h8 vv = *(const h8*)(vb + ((c ^ sx) << 3));
#pragma unroll
                    for (int e = 0; e < 8; ++e)
                        accv[c * 8 + e] = fmaf((float)vv[e], p, accv[c * 8 + e]);
                }
            }
        }
        const float inv = 1.f / lsum;
        u16* oph = oh + pixg * CDIM + head * HDIM;
        u16* opl = ol + pixg * CDIM + head * HDIM;
#pragma unroll
        for (int d4 = 0; d4 < 8; ++d4) {
            float4 o;
            o.x = accv[d4 * 4 + 0] * inv;
            o.y = accv[d4 * 4 + 1] * inv;
            o.z = accv[d4 * 4 + 2] * inv;
            o.w = accv[d4 * 4 + 3] * inv;
            ushort4 h4, l4;
            h4.x = f2bf(o.x); l4.x = f2bf(o.x - bf2f(h4.x));
            h4.y = f2bf(o.y); l4.y = f2bf(o.y - bf2f(h4.y));
            h4.z = f2bf(o.z); l4.z = f2bf(o.z - bf2f(h4.z));
            h4.w = f2bf(o.w); l4.w = f2bf(o.w - bf2f(h4.w));
            *(ushort4*)(oph + d4 * 4) = h4;
            *(ushort4*)(opl + d4 * 4) = l4;
        }
    }
}

// ---------------------------------------------------------------------------
extern "C" void kernel_launch(void* const* d_in, const int* in_sizes, int n_in,
                              void* d_out, int out_size, void* d_ws, size_t ws_size,
                              hipStream_t stream)
{
    const float* x      = (const float*)d_in[0];
    const float* w_qkv  = (const float*)d_in[1];
    const float* b_qkv  = (const float*)d_in[2];
    const float* rpb    = (const float*)d_in[3];
    const float* w_proj = (const float*)d_in[4];
    const float* b_proj = (const float*)d_in[5];
    float* outp = (float*)d_out;

    char* p = (char*)d_ws;
    float* qkv = (float*)p;  p += (size_t)NPIX * QKV_N * 4;
    u16* xh = (u16*)p;       p += (size_t)NPIX * CDIM * 2;
    u16* xl = (u16*)p;       p += (size_t)NPIX * CDIM * 2;
    u16* wqh = (u16*)p;      p += (size_t)QKV_N * CDIM * 2;
    u16* wql = (u16*)p;      p += (size_t)QKV_N * CDIM * 2;
    u16* wph = (u16*)p;      p += (size_t)CDIM * CDIM * 2;
    u16* wpl = (u16*)p;      p += (size_t)CDIM * CDIM * 2;
    u16* ath = xh;
    u16* atl = xl;

    {
        const int n4 = NPIX * CDIM / 4;
        split_f32<<<(n4 + 255) / 256, 256, 0, stream>>>(x, xh, xl, n4);
        transpose_split<<<(CDIM * QKV_N + 255) / 256, 256, 0, stream>>>(
            w_qkv, wqh, wql, CDIM, QKV_N);
        transpose_split<<<(CDIM * CDIM + 255) / 256, 256, 0, stream>>>(
            w_proj, wph, wpl, CDIM, CDIM);
    }
    gemm_split_bf16<<<(NPIX / 128) * (QKV_N / 128), 256, 0, stream>>>(
        xh, xl, wqh, wql, b_qkv, qkv, NPIX, QKV_N, CDIM);
    natten2d<<<dim3(16, NHEADS, NBATCH), 256, 0, stream>>>(qkv, rpb, ath, atl);
    gemm_split_bf16<<<(NPIX / 128) * (CDIM / 128), 256, 0, stream>>>(
        ath, atl, wph, wpl, b_proj, outp, NPIX, CDIM, CDIM);
}

// Round 10
// 1499.025 us; speedup vs baseline: 1.6632x; 1.6632x over previous
//
#include <hip/hip_runtime.h>
#include <cstdint>
#include <cstddef>

#define HWDIM 56
#define NBATCH 8
#define NHEADS 16
#define HDIM 32
#define CDIM 512
#define QKV_N 1536
#define KSZ 7
#define RAD 3
#define NPIX (NBATCH*HWDIM*HWDIM)          // 25088
#define SCALE 0.17677669529663687f         // 32^-0.5

typedef unsigned short u16;
typedef __bf16 bf16x8 __attribute__((ext_vector_type(8)));
typedef float  f32x4  __attribute__((ext_vector_type(4)));
typedef _Float16 h2 __attribute__((ext_vector_type(2)));
typedef _Float16 h8 __attribute__((ext_vector_type(8)));

// ---- bf16 helpers (RNE) ----
__device__ __forceinline__ u16 f2bf(float x) {
    union { float f; unsigned u; } v; v.f = x;
    unsigned r = v.u + 0x7fff + ((v.u >> 16) & 1);
    return (u16)(r >> 16);
}
__device__ __forceinline__ float bf2f(u16 h) {
    union { float f; unsigned u; } v; v.u = ((unsigned)h) << 16; return v.f;
}

// async global->LDS, 16B per lane (lane-linear LDS dest per m104/m108)
__device__ __forceinline__ void gload16(const void* g, void* l) {
    __builtin_amdgcn_global_load_lds(
        (const __attribute__((address_space(1))) unsigned int*)g,
        (__attribute__((address_space(3))) unsigned int*)l, 16, 0, 0);
}

// ---------------------------------------------------------------------------
// prep: fp32 -> (hi, lo) bf16 split, elementwise (vectorized x4)
// ---------------------------------------------------------------------------
__global__ __launch_bounds__(256)
void split_f32(const float* __restrict__ in, u16* __restrict__ hi,
               u16* __restrict__ lo, int n4)
{
    int i = blockIdx.x * 256 + threadIdx.x;
    if (i >= n4) return;
    float4 v = ((const float4*)in)[i];
    ushort4 h, l;
    h.x = f2bf(v.x); l.x = f2bf(v.x - bf2f(h.x));
    h.y = f2bf(v.y); l.y = f2bf(v.y - bf2f(h.y));
    h.z = f2bf(v.z); l.z = f2bf(v.z - bf2f(h.z));
    h.w = f2bf(v.w); l.w = f2bf(v.w - bf2f(h.w));
    ((ushort4*)hi)[i] = h;
    ((ushort4*)lo)[i] = l;
}

// ---------------------------------------------------------------------------
// prep: W[K][N] fp32 -> Wt[N][K] (hi, lo) bf16
// ---------------------------------------------------------------------------
__global__ __launch_bounds__(256)
void transpose_split(const float* __restrict__ w, u16* __restrict__ th,
                     u16* __restrict__ tl, int K, int N)
{
    int idx = blockIdx.x * 256 + threadIdx.x;
    if (idx >= K * N) return;
    int n = idx / K, k = idx - n * K;
    float v = w[(size_t)k * N + n];
    u16 h = f2bf(v);
    th[idx] = h;
    tl[idx] = f2bf(v - bf2f(h));
}

// ---------------------------------------------------------------------------
// split-bf16 MFMA GEMM + bias (r3/r5-proven) + XCD-aware blockIdx swizzle.
// Swizzle: XCD k (round-robin on original blockIdx, k = orig & 7) processes
// a CONTIGUOUS chunk of output tiles -> A-panel reuse becomes L2-local.
// Bijective because gridDim.x % 8 == 0 (2352, 784). Pure index permutation,
// numerics untouched.
// ---------------------------------------------------------------------------
__global__ __launch_bounds__(256, 2)
void gemm_split_bf16(const u16* __restrict__ Ah, const u16* __restrict__ Al,
                     const u16* __restrict__ Bh, const u16* __restrict__ Bl,
                     const float* __restrict__ bias, float* __restrict__ C,
                     int M, int N, int K)
{
    __shared__ __bf16 sAh[128 * 32], sAl[128 * 32];
    __shared__ __bf16 sBh[128 * 32], sBl[128 * 32];

    const int nbx  = N >> 7;
    const int cpx  = gridDim.x >> 3;          // chunk per XCD
    const int bid  = (blockIdx.x & 7) * cpx + (blockIdx.x >> 3);
    const int bx   = bid % nbx;
    const int by   = bid / nbx;
    const int m0   = by << 7;
    const int n0   = bx << 7;
    const int tid  = threadIdx.x;
    const int lane = tid & 63;
    const int wid  = tid >> 6;
    const int wr   = wid >> 1;
    const int wc   = wid & 1;

    f32x4 acc[4][4];
#pragma unroll
    for (int m = 0; m < 4; ++m)
#pragma unroll
        for (int n = 0; n < 4; ++n)
#pragma unroll
            for (int j = 0; j < 4; ++j) acc[m][n][j] = 0.f;

    int a_off[4], b_off[4];
#pragma unroll
    for (int m = 0; m < 4; ++m) {
        int row = wr * 64 + m * 16 + (lane & 15);
        int kb  = lane >> 4;
        a_off[m] = row * 32 + (kb ^ ((row >> 1) & 3)) * 8;
    }
#pragma unroll
    for (int n = 0; n < 4; ++n) {
        int row = wc * 64 + n * 16 + (lane & 15);
        int kb  = lane >> 4;
        b_off[n] = row * 32 + (kb ^ ((row >> 1) & 3)) * 8;
    }

    int s_row[2], s_kbg[2], s_lds[2];
#pragma unroll
    for (int it = 0; it < 2; ++it) {
        int s = it * 256 + tid;
        int row = s >> 2, kbs = s & 3;
        s_row[it] = row;
        s_kbg[it] = kbs ^ ((row >> 1) & 3);
        s_lds[it] = s * 8;
    }

    for (int kt = 0; kt < K; kt += 32) {
#pragma unroll
        for (int it = 0; it < 2; ++it) {
            const size_t ga = (size_t)(m0 + s_row[it]) * K + kt + s_kbg[it] * 8;
            const size_t gb = (size_t)(n0 + s_row[it]) * K + kt + s_kbg[it] * 8;
            gload16(Ah + ga, (void*)(sAh + s_lds[it]));
            gload16(Al + ga, (void*)(sAl + s_lds[it]));
            gload16(Bh + gb, (void*)(sBh + s_lds[it]));
            gload16(Bl + gb, (void*)(sBl + s_lds[it]));
        }
        __syncthreads();

        bf16x8 ah[4], al[4], bh[4], bl[4];
#pragma unroll
        for (int m = 0; m < 4; ++m) {
            ah[m] = *(const bf16x8*)(sAh + a_off[m]);
            al[m] = *(const bf16x8*)(sAl + a_off[m]);
        }
#pragma unroll
        for (int n = 0; n < 4; ++n) {
            bh[n] = *(const bf16x8*)(sBh + b_off[n]);
            bl[n] = *(const bf16x8*)(sBl + b_off[n]);
        }
#pragma unroll
        for (int m = 0; m < 4; ++m)
#pragma unroll
            for (int n = 0; n < 4; ++n) {
                acc[m][n] = __builtin_amdgcn_mfma_f32_16x16x32_bf16(al[m], bh[n], acc[m][n], 0, 0, 0);
                acc[m][n] = __builtin_amdgcn_mfma_f32_16x16x32_bf16(ah[m], bl[n], acc[m][n], 0, 0, 0);
                acc[m][n] = __builtin_amdgcn_mfma_f32_16x16x32_bf16(ah[m], bh[n], acc[m][n], 0, 0, 0);
            }
        __syncthreads();
    }

#pragma unroll
    for (int m = 0; m < 4; ++m) {
        const int rbase = m0 + wr * 64 + m * 16 + (lane >> 4) * 4;
#pragma unroll
        for (int n = 0; n < 4; ++n) {
            const int col = n0 + wc * 64 + n * 16 + (lane & 15);
            const float bv = bias[col];
#pragma unroll
            for (int j = 0; j < 4; ++j)
                C[(size_t)(rbase + j) * N + col] = acc[m][n][j] + bv;
        }
    }
}

// ---------------------------------------------------------------------------
// NATTEN 7x7, v2c: fp16 LDS tiles + fdot2 QK^T with plain launch bounds.
// r5's __launch_bounds__(256,4) forced 64 VGPR -> logit[49]/accv[32]
// spilled to scratch -> 5.9 GB HBM spill traffic, 2.2 ms, VALUBusy 2.9%.
// Plain (256) lets the ~110-VGPR live set sit in the 128-VGPR tier
// (4 waves/SIMD); LDS 31 KB allows 5 blocks/CU so LDS is not the cap.
// ---------------------------------------------------------------------------
__global__ __launch_bounds__(256)
void natten2d(const float* __restrict__ qkv, const float* __restrict__ rpb,
              u16* __restrict__ oh, u16* __restrict__ ol)
{
    __shared__ _Float16 tile[484 * 32];   // 30,976 B; [pix][chunk^((pix>>1)&3)]

    const int tix  = blockIdx.x & 3;
    const int tiy  = blockIdx.x >> 2;
    const int head = blockIdx.y;
    const int b    = blockIdx.z;
    const int r0   = tiy * 16;
    const int c0   = tix * 16;
    const int bh0  = min(max(r0 - RAD, 0), HWDIM - 22);
    const int cw0  = min(max(c0 - RAD, 0), HWDIM - 22);

    const int tid = threadIdx.x;
    const int ph  = tid >> 4;
    const int pw  = tid & 15;
    const int h   = r0 + ph;
    const int w   = c0 + pw;
    const bool active = (h < HWDIM) && (w < HWDIM);
    const int hc = min(h, HWDIM - 1);
    const int wc = min(w, HWDIM - 1);
    const size_t pixg = (size_t)(b * HWDIM + hc) * HWDIM + wc;

    // ---- load q, scale, convert to fp16 pairs ----
    h2 q2[16];
    {
        const float* qp = qkv + pixg * QKV_N + head * HDIM;
#pragma unroll
        for (int d4 = 0; d4 < 8; ++d4) {
            float4 v = *(const float4*)(qp + d4 * 4);
            h2 t0, t1;
            t0[0] = (_Float16)(v.x * SCALE); t0[1] = (_Float16)(v.y * SCALE);
            t1[0] = (_Float16)(v.z * SCALE); t1[1] = (_Float16)(v.w * SCALE);
            q2[d4 * 2]     = t0;
            q2[d4 * 2 + 1] = t1;
        }
    }

    const int sh      = min(max(h - RAD, 0), HWDIM - KSZ);
    const int sw      = min(max(w - RAD, 0), HWDIM - KSZ);
    const int lh0     = sh - bh0;
    const int lw0     = sw - cw0;
    const int bh_base = sh + (KSZ - 1) - h;   // valid (0..6) only when active
    const int bw_base = sw + (KSZ - 1) - w;

    // ---- stage K into LDS (fp32 -> fp16), all threads ----
    for (int i = tid; i < 484 * 4; i += 256) {
        const int pix = i >> 2;
        const int c   = i & 3;
        const int row = pix / 22;
        const int col = pix - row * 22;
        const float* src = qkv +
            ((size_t)((b * HWDIM + bh0 + row) * HWDIM + cw0 + col)) * QKV_N
            + CDIM + head * HDIM + c * 8;
        float4 v0 = *(const float4*)src;
        float4 v1 = *(const float4*)(src + 4);
        h8 hv;
        hv[0] = (_Float16)v0.x; hv[1] = (_Float16)v0.y;
        hv[2] = (_Float16)v0.z; hv[3] = (_Float16)v0.w;
        hv[4] = (_Float16)v1.x; hv[5] = (_Float16)v1.y;
        hv[6] = (_Float16)v1.z; hv[7] = (_Float16)v1.w;
        *(h8*)&tile[pix * 32 + ((c ^ ((pix >> 1) & 3)) << 3)] = hv;
    }
    __syncthreads();

    // ---- QK^T: 49 logits per pixel (active threads only) ----
    float logit[49];
    float mmax = -1e30f;
    if (active) {
#pragma unroll
        for (int a = 0; a < KSZ; ++a) {
#pragma unroll
            for (int bb = 0; bb < KSZ; ++bb) {
                const int pix = (lh0 + a) * 22 + (lw0 + bb);
                const int sx  = (pix >> 1) & 3;
                const _Float16* kb = &tile[pix * 32];
                float s = 0.f;
#pragma unroll
                for (int c = 0; c < 4; ++c) {
                    h8 kv = *(const h8*)(kb + ((c ^ sx) << 3));
                    h2 p0 = __builtin_shufflevector(kv, kv, 0, 1);
                    h2 p1 = __builtin_shufflevector(kv, kv, 2, 3);
                    h2 p2 = __builtin_shufflevector(kv, kv, 4, 5);
                    h2 p3 = __builtin_shufflevector(kv, kv, 6, 7);
                    s = __builtin_amdgcn_fdot2(q2[c * 4 + 0], p0, s, false);
                    s = __builtin_amdgcn_fdot2(q2[c * 4 + 1], p1, s, false);
                    s = __builtin_amdgcn_fdot2(q2[c * 4 + 2], p2, s, false);
                    s = __builtin_amdgcn_fdot2(q2[c * 4 + 3], p3, s, false);
                }
                s += rpb[head * 169 + (bh_base + a) * 13 + (bw_base + bb)];
                logit[a * KSZ + bb] = s;
                mmax = fmaxf(mmax, s);
            }
        }
    }
    __syncthreads();   // all K reads complete before V overwrites the buffer

    // ---- stage V into LDS (same buffer), all threads ----
    for (int i = tid; i < 484 * 4; i += 256) {
        const int pix = i >> 2;
        const int c   = i & 3;
        const int row = pix / 22;
        const int col = pix - row * 22;
        const float* src = qkv +
            ((size_t)((b * HWDIM + bh0 + row) * HWDIM + cw0 + col)) * QKV_N
            + 2 * CDIM + head * HDIM + c * 8;
        float4 v0 = *(const float4*)src;
        float4 v1 = *(const float4*)(src + 4);
        h8 hv;
        hv[0] = (_Float16)v0.x; hv[1] = (_Float16)v0.y;
        hv[2] = (_Float16)v0.z; hv[3] = (_Float16)v0.w;
        hv[4] = (_Float16)v1.x; hv[5] = (_Float16)v1.y;
        hv[6] = (_Float16)v1.z; hv[7] = (_Float16)v1.w;
        *(h8*)&tile[pix * 32 + ((c ^ ((pix >> 1) & 3)) << 3)] = hv;
    }
    __syncthreads();

    // ---- softmax + PV + store (active threads only) ----
    if (active) {
        float accv[32];
#pragma unroll
        for (int d = 0; d < 32; ++d) accv[d] = 0.f;
        float lsum = 0.f;
#pragma unroll
        for (int a = 0; a < KSZ; ++a) {
#pragma unroll
            for (int bb = 0; bb < KSZ; ++bb) {
                const float p = __expf(logit[a * KSZ + bb] - mmax);
                lsum += p;
                const int pix = (lh0 + a) * 22 + (lw0 + bb);
                const int sx  = (pix >> 1) & 3;
                const _Float16* vb = &tile[pix * 32];
#pragma unroll
                for (int c = 0; c < 4; ++c) {
                    h8 vv = *(const h8*)(vb + ((c ^ sx) << 3));
#pragma unroll
                    for (int e = 0; e < 8; ++e)
                        accv[c * 8 + e] = fmaf((float)vv[e], p, accv[c * 8 + e]);
                }
            }
        }
        const float inv = 1.f / lsum;
        u16* oph = oh + pixg * CDIM + head * HDIM;
        u16* opl = ol + pixg * CDIM + head * HDIM;
#pragma unroll
        for (int d4 = 0; d4 < 8; ++d4) {
            float4 o;
            o.x = accv[d4 * 4 + 0] * inv;
            o.y = accv[d4 * 4 + 1] * inv;
            o.z = accv[d4 * 4 + 2] * inv;
            o.w = accv[d4 * 4 + 3] * inv;
            ushort4 h4, l4;
            h4.x = f2bf(o.x); l4.x = f2bf(o.x - bf2f(h4.x));
            h4.y = f2bf(o.y); l4.y = f2bf(o.y - bf2f(h4.y));
            h4.z = f2bf(o.z); l4.z = f2bf(o.z - bf2f(h4.z));
            h4.w = f2bf(o.w); l4.w = f2bf(o.w - bf2f(h4.w));
            *(ushort4*)(oph + d4 * 4) = h4;
            *(ushort4*)(opl + d4 * 4) = l4;
        }
    }
}

// ---------------------------------------------------------------------------
extern "C" void kernel_launch(void* const* d_in, const int* in_sizes, int n_in,
                              void* d_out, int out_size, void* d_ws, size_t ws_size,
                              hipStream_t stream)
{
    const float* x      = (const float*)d_in[0];
    const float* w_qkv  = (const float*)d_in[1];
    const float* b_qkv  = (const float*)d_in[2];
    const float* rpb    = (const float*)d_in[3];
    const float* w_proj = (const float*)d_in[4];
    const float* b_proj = (const float*)d_in[5];
    float* outp = (float*)d_out;

    char* p = (char*)d_ws;
    float* qkv = (float*)p;  p += (size_t)NPIX * QKV_N * 4;
    u16* xh = (u16*)p;       p += (size_t)NPIX * CDIM * 2;
    u16* xl = (u16*)p;       p += (size_t)NPIX * CDIM * 2;
    u16* wqh = (u16*)p;      p += (size_t)QKV_N * CDIM * 2;
    u16* wql = (u16*)p;      p += (size_t)QKV_N * CDIM * 2;
    u16* wph = (u16*)p;      p += (size_t)CDIM * CDIM * 2;
    u16* wpl = (u16*)p;      p += (size_t)CDIM * CDIM * 2;
    u16* ath = xh;
    u16* atl = xl;

    {
        const int n4 = NPIX * CDIM / 4;
        split_f32<<<(n4 + 255) / 256, 256, 0, stream>>>(x, xh, xl, n4);
        transpose_split<<<(CDIM * QKV_N + 255) / 256, 256, 0, stream>>>(
            w_qkv, wqh, wql, CDIM, QKV_N);
        transpose_split<<<(CDIM * CDIM + 255) / 256, 256, 0, stream>>>(
            w_proj, wph, wpl, CDIM, CDIM);
    }
    gemm_split_bf16<<<(NPIX / 128) * (QKV_N / 128), 256, 0, stream>>>(
        xh, xl, wqh, wql, b_qkv, qkv, NPIX, QKV_N, CDIM);
    natten2d<<<dim3(16, NHEADS, NBATCH), 256, 0, stream>>>(qkv, rpb, ath, atl);
    gemm_split_bf16<<<(NPIX / 128) * (CDIM / 128), 256, 0, stream>>>(
        ath, atl, wph, wpl, b_proj, outp, NPIX, CDIM, CDIM);
}

// Round 11
// 433.793 us; speedup vs baseline: 5.7474x; 3.4556x over previous
//
#include <hip/hip_runtime.h>
#include <cstdint>
#include <cstddef>

#define HWDIM 56
#define NBATCH 8
#define NHEADS 16
#define HDIM 32
#define CDIM 512
#define QKV_N 1536
#define KSZ 7
#define RAD 3
#define NPIX (NBATCH*HWDIM*HWDIM)          // 25088
#define SCALE 0.17677669529663687f         // 32^-0.5

typedef unsigned short u16;
typedef __bf16 bf16x8 __attribute__((ext_vector_type(8)));
typedef float  f32x4  __attribute__((ext_vector_type(4)));

// ---- bf16 helpers (RNE) ----
__device__ __forceinline__ u16 f2bf(float x) {
    union { float f; unsigned u; } v; v.f = x;
    unsigned r = v.u + 0x7fff + ((v.u >> 16) & 1);
    return (u16)(r >> 16);
}
__device__ __forceinline__ float bf2f(u16 h) {
    union { float f; unsigned u; } v; v.u = ((unsigned)h) << 16; return v.f;
}

// async global->LDS, 16B per lane (lane-linear LDS dest per m104/m108)
__device__ __forceinline__ void gload16(const void* g, void* l) {
    __builtin_amdgcn_global_load_lds(
        (const __attribute__((address_space(1))) unsigned int*)g,
        (__attribute__((address_space(3))) unsigned int*)l, 16, 0, 0);
}

// ---------------------------------------------------------------------------
// prep: fp32 -> (hi, lo) bf16 split, elementwise (vectorized x4)
// ---------------------------------------------------------------------------
__global__ __launch_bounds__(256)
void split_f32(const float* __restrict__ in, u16* __restrict__ hi,
               u16* __restrict__ lo, int n4)
{
    int i = blockIdx.x * 256 + threadIdx.x;
    if (i >= n4) return;
    float4 v = ((const float4*)in)[i];
    ushort4 h, l;
    h.x = f2bf(v.x); l.x = f2bf(v.x - bf2f(h.x));
    h.y = f2bf(v.y); l.y = f2bf(v.y - bf2f(h.y));
    h.z = f2bf(v.z); l.z = f2bf(v.z - bf2f(h.z));
    h.w = f2bf(v.w); l.w = f2bf(v.w - bf2f(h.w));
    ((ushort4*)hi)[i] = h;
    ((ushort4*)lo)[i] = l;
}

// ---------------------------------------------------------------------------
// prep: W[K][N] fp32 -> Wt[N][K] (hi, lo) bf16
// ---------------------------------------------------------------------------
__global__ __launch_bounds__(256)
void transpose_split(const float* __restrict__ w, u16* __restrict__ th,
                     u16* __restrict__ tl, int K, int N)
{
    int idx = blockIdx.x * 256 + threadIdx.x;
    if (idx >= K * N) return;
    int n = idx / K, k = idx - n * K;
    float v = w[(size_t)k * N + n];
    u16 h = f2bf(v);
    th[idx] = h;
    tl[idx] = f2bf(v - bf2f(h));
}

// ---------------------------------------------------------------------------
// split-bf16 MFMA GEMM + bias (r3/r5/r10-proven) + XCD-aware blockIdx
// swizzle (bijective: gridDim.x % 8 == 0 for 2352 and 784). Pure index
// permutation, numerics untouched.
// ---------------------------------------------------------------------------
__global__ __launch_bounds__(256, 2)
void gemm_split_bf16(const u16* __restrict__ Ah, const u16* __restrict__ Al,
                     const u16* __restrict__ Bh, const u16* __restrict__ Bl,
                     const float* __restrict__ bias, float* __restrict__ C,
                     int M, int N, int K)
{
    __shared__ __bf16 sAh[128 * 32], sAl[128 * 32];
    __shared__ __bf16 sBh[128 * 32], sBl[128 * 32];

    const int nbx  = N >> 7;
    const int cpx  = gridDim.x >> 3;          // chunk per XCD
    const int bid  = (blockIdx.x & 7) * cpx + (blockIdx.x >> 3);
    const int bx   = bid % nbx;
    const int by   = bid / nbx;
    const int m0   = by << 7;
    const int n0   = bx << 7;
    const int tid  = threadIdx.x;
    const int lane = tid & 63;
    const int wid  = tid >> 6;
    const int wr   = wid >> 1;
    const int wc   = wid & 1;

    f32x4 acc[4][4];
#pragma unroll
    for (int m = 0; m < 4; ++m)
#pragma unroll
        for (int n = 0; n < 4; ++n)
#pragma unroll
            for (int j = 0; j < 4; ++j) acc[m][n][j] = 0.f;

    int a_off[4], b_off[4];
#pragma unroll
    for (int m = 0; m < 4; ++m) {
        int row = wr * 64 + m * 16 + (lane & 15);
        int kb  = lane >> 4;
        a_off[m] = row * 32 + (kb ^ ((row >> 1) & 3)) * 8;
    }
#pragma unroll
    for (int n = 0; n < 4; ++n) {
        int row = wc * 64 + n * 16 + (lane & 15);
        int kb  = lane >> 4;
        b_off[n] = row * 32 + (kb ^ ((row >> 1) & 3)) * 8;
    }

    int s_row[2], s_kbg[2], s_lds[2];
#pragma unroll
    for (int it = 0; it < 2; ++it) {
        int s = it * 256 + tid;
        int row = s >> 2, kbs = s & 3;
        s_row[it] = row;
        s_kbg[it] = kbs ^ ((row >> 1) & 3);
        s_lds[it] = s * 8;
    }

    for (int kt = 0; kt < K; kt += 32) {
#pragma unroll
        for (int it = 0; it < 2; ++it) {
            const size_t ga = (size_t)(m0 + s_row[it]) * K + kt + s_kbg[it] * 8;
            const size_t gb = (size_t)(n0 + s_row[it]) * K + kt + s_kbg[it] * 8;
            gload16(Ah + ga, (void*)(sAh + s_lds[it]));
            gload16(Al + ga, (void*)(sAl + s_lds[it]));
            gload16(Bh + gb, (void*)(sBh + s_lds[it]));
            gload16(Bl + gb, (void*)(sBl + s_lds[it]));
        }
        __syncthreads();

        bf16x8 ah[4], al[4], bh[4], bl[4];
#pragma unroll
        for (int m = 0; m < 4; ++m) {
            ah[m] = *(const bf16x8*)(sAh + a_off[m]);
            al[m] = *(const bf16x8*)(sAl + a_off[m]);
        }
#pragma unroll
        for (int n = 0; n < 4; ++n) {
            bh[n] = *(const bf16x8*)(sBh + b_off[n]);
            bl[n] = *(const bf16x8*)(sBl + b_off[n]);
        }
#pragma unroll
        for (int m = 0; m < 4; ++m)
#pragma unroll
            for (int n = 0; n < 4; ++n) {
                acc[m][n] = __builtin_amdgcn_mfma_f32_16x16x32_bf16(al[m], bh[n], acc[m][n], 0, 0, 0);
                acc[m][n] = __builtin_amdgcn_mfma_f32_16x16x32_bf16(ah[m], bl[n], acc[m][n], 0, 0, 0);
                acc[m][n] = __builtin_amdgcn_mfma_f32_16x16x32_bf16(ah[m], bh[n], acc[m][n], 0, 0, 0);
            }
        __syncthreads();
    }

#pragma unroll
    for (int m = 0; m < 4; ++m) {
        const int rbase = m0 + wr * 64 + m * 16 + (lane >> 4) * 4;
#pragma unroll
        for (int n = 0; n < 4; ++n) {
            const int col = n0 + wc * 64 + n * 16 + (lane & 15);
            const float bv = bias[col];
#pragma unroll
            for (int j = 0; j < 4; ++j)
                C[(size_t)(rbase + j) * N + col] = acc[m][n][j] + bv;
        }
    }
}

// ---------------------------------------------------------------------------
// NATTEN 7x7 — REVERTED to the r3-proven fp32 body (153.7 us, 124 VGPR,
// zero spill). The fp16-LDS variants both hit register-allocator
// pathologies: r5 (launch_bounds(256,4)) capped at 64 VGPR -> spill;
// r10 (unbounded) ballooned to 256 VGPR AND spilled 1.27 GB/dispatch
// (hoisted h8 load temporaries across the unrolled tap loop). fp32 body
// with float4 LDS + plain fmaf is the known-good codegen.
// ---------------------------------------------------------------------------
__global__ __launch_bounds__(256)
void natten2d(const float* __restrict__ qkv, const float* __restrict__ rpb,
              u16* __restrict__ oh, u16* __restrict__ ol)
{
    __shared__ float tile[484 * 32];   // 61,952 B; [pix][slot^(pix&7)]

    const int tix  = blockIdx.x & 3;
    const int tiy  = blockIdx.x >> 2;
    const int head = blockIdx.y;
    const int b    = blockIdx.z;
    const int r0   = tiy * 16;
    const int c0   = tix * 16;
    const int bh0  = min(max(r0 - RAD, 0), HWDIM - 22);
    const int cw0  = min(max(c0 - RAD, 0), HWDIM - 22);

    const int tid = threadIdx.x;
    const int ph  = tid >> 4;
    const int pw  = tid & 15;
    const int h   = r0 + ph;
    const int w   = c0 + pw;
    const bool active = (h < HWDIM) && (w < HWDIM);
    const int hc = min(h, HWDIM - 1);
    const int wc = min(w, HWDIM - 1);
    const size_t pixg = (size_t)(b * HWDIM + hc) * HWDIM + wc;

    // ---- load q (scaled) ----
    float q[32];
    {
        const float* qp = qkv + pixg * QKV_N + head * HDIM;
#pragma unroll
        for (int d4 = 0; d4 < 8; ++d4) {
            float4 v = *(const float4*)(qp + d4 * 4);
            q[d4 * 4 + 0] = v.x * SCALE;
            q[d4 * 4 + 1] = v.y * SCALE;
            q[d4 * 4 + 2] = v.z * SCALE;
            q[d4 * 4 + 3] = v.w * SCALE;
        }
    }

    const int sh      = min(max(h - RAD, 0), HWDIM - KSZ);
    const int sw      = min(max(w - RAD, 0), HWDIM - KSZ);
    const int lh0     = sh - bh0;
    const int lw0     = sw - cw0;
    const int bh_base = sh + (KSZ - 1) - h;
    const int bw_base = sw + (KSZ - 1) - w;

    // ---- stage K into LDS ----
    for (int i = tid; i < 484 * 8; i += 256) {
        const int pix = i >> 3;
        const int d4  = i & 7;
        const int row = pix / 22;
        const int col = pix - row * 22;
        const float4 kv = *(const float4*)(qkv +
            ((size_t)((b * HWDIM + bh0 + row) * HWDIM + cw0 + col)) * QKV_N
            + CDIM + head * HDIM + d4 * 4);
        *(float4*)&tile[pix * 32 + (((d4 ^ pix) & 7) << 2)] = kv;
    }
    __syncthreads();

    // ---- QK^T: 49 logits per pixel ----
    float logit[49];
    float mmax = -1e30f;
    if (active) {
#pragma unroll
        for (int a = 0; a < KSZ; ++a) {
#pragma unroll
            for (int bb = 0; bb < KSZ; ++bb) {
                const int pix = (lh0 + a) * 22 + (lw0 + bb);
                const int swz = pix & 7;
                float s = 0.f;
#pragma unroll
                for (int d4 = 0; d4 < 8; ++d4) {
                    const float4 kv = *(const float4*)&tile[pix * 32 + (((d4 ^ swz) & 7) << 2)];
                    s = fmaf(q[d4 * 4 + 0], kv.x, s);
                    s = fmaf(q[d4 * 4 + 1], kv.y, s);
                    s = fmaf(q[d4 * 4 + 2], kv.z, s);
                    s = fmaf(q[d4 * 4 + 3], kv.w, s);
                }
                s += rpb[head * 169 + (bh_base + a) * 13 + (bw_base + bb)];
                logit[a * KSZ + bb] = s;
                mmax = fmaxf(mmax, s);
            }
        }
    }
    __syncthreads();   // all K reads complete before V overwrites the buffer

    // ---- stage V into LDS (same buffer) ----
    for (int i = tid; i < 484 * 8; i += 256) {
        const int pix = i >> 3;
        const int d4  = i & 7;
        const int row = pix / 22;
        const int col = pix - row * 22;
        const float4 vv = *(const float4*)(qkv +
            ((size_t)((b * HWDIM + bh0 + row) * HWDIM + cw0 + col)) * QKV_N
            + 2 * CDIM + head * HDIM + d4 * 4);
        *(float4*)&tile[pix * 32 + (((d4 ^ pix) & 7) << 2)] = vv;
    }
    __syncthreads();

    // ---- softmax + PV ----
    if (active) {
        float accv[32];
#pragma unroll
        for (int d = 0; d < 32; ++d) accv[d] = 0.f;
        float lsum = 0.f;
#pragma unroll
        for (int a = 0; a < KSZ; ++a) {
#pragma unroll
            for (int bb = 0; bb < KSZ; ++bb) {
                const float p = __expf(logit[a * KSZ + bb] - mmax);
                lsum += p;
                const int pix = (lh0 + a) * 22 + (lw0 + bb);
                const int swz = pix & 7;
#pragma unroll
                for (int d4 = 0; d4 < 8; ++d4) {
                    const float4 vv = *(const float4*)&tile[pix * 32 + (((d4 ^ swz) & 7) << 2)];
                    accv[d4 * 4 + 0] = fmaf(p, vv.x, accv[d4 * 4 + 0]);
                    accv[d4 * 4 + 1] = fmaf(p, vv.y, accv[d4 * 4 + 1]);
                    accv[d4 * 4 + 2] = fmaf(p, vv.z, accv[d4 * 4 + 2]);
                    accv[d4 * 4 + 3] = fmaf(p, vv.w, accv[d4 * 4 + 3]);
                }
            }
        }
        const float inv = 1.f / lsum;
        u16* oph = oh + pixg * CDIM + head * HDIM;
        u16* opl = ol + pixg * CDIM + head * HDIM;
#pragma unroll
        for (int d4 = 0; d4 < 8; ++d4) {
            float4 o;
            o.x = accv[d4 * 4 + 0] * inv;
            o.y = accv[d4 * 4 + 1] * inv;
            o.z = accv[d4 * 4 + 2] * inv;
            o.w = accv[d4 * 4 + 3] * inv;
            ushort4 h4, l4;
            h4.x = f2bf(o.x); l4.x = f2bf(o.x - bf2f(h4.x));
            h4.y = f2bf(o.y); l4.y = f2bf(o.y - bf2f(h4.y));
            h4.z = f2bf(o.z); l4.z = f2bf(o.z - bf2f(h4.z));
            h4.w = f2bf(o.w); l4.w = f2bf(o.w - bf2f(h4.w));
            *(ushort4*)(oph + d4 * 4) = h4;
            *(ushort4*)(opl + d4 * 4) = l4;
        }
    }
}

// ---------------------------------------------------------------------------
extern "C" void kernel_launch(void* const* d_in, const int* in_sizes, int n_in,
                              void* d_out, int out_size, void* d_ws, size_t ws_size,
                              hipStream_t stream)
{
    const float* x      = (const float*)d_in[0];
    const float* w_qkv  = (const float*)d_in[1];
    const float* b_qkv  = (const float*)d_in[2];
    const float* rpb    = (const float*)d_in[3];
    const float* w_proj = (const float*)d_in[4];
    const float* b_proj = (const float*)d_in[5];
    float* outp = (float*)d_out;

    char* p = (char*)d_ws;
    float* qkv = (float*)p;  p += (size_t)NPIX * QKV_N * 4;
    u16* xh = (u16*)p;       p += (size_t)NPIX * CDIM * 2;
    u16* xl = (u16*)p;       p += (size_t)NPIX * CDIM * 2;
    u16* wqh = (u16*)p;      p += (size_t)QKV_N * CDIM * 2;
    u16* wql = (u16*)p;      p += (size_t)QKV_N * CDIM * 2;
    u16* wph = (u16*)p;      p += (size_t)CDIM * CDIM * 2;
    u16* wpl = (u16*)p;      p += (size_t)CDIM * CDIM * 2;
    u16* ath = xh;
    u16* atl = xl;

    {
        const int n4 = NPIX * CDIM / 4;
        split_f32<<<(n4 + 255) / 256, 256, 0, stream>>>(x, xh, xl, n4);
        transpose_split<<<(CDIM * QKV_N + 255) / 256, 256, 0, stream>>>(
            w_qkv, wqh, wql, CDIM, QKV_N);
        transpose_split<<<(CDIM * CDIM + 255) / 256, 256, 0, stream>>>(
            w_proj, wph, wpl, CDIM, CDIM);
    }
    gemm_split_bf16<<<(NPIX / 128) * (QKV_N / 128), 256, 0, stream>>>(
        xh, xl, wqh, wql, b_qkv, qkv, NPIX, QKV_N, CDIM);
    natten2d<<<dim3(16, NHEADS, NBATCH), 256, 0, stream>>>(qkv, rpb, ath, atl);
    gemm_split_bf16<<<(NPIX / 128) * (CDIM / 128), 256, 0, stream>>>(
        ath, atl, wph, wpl, b_proj, outp, NPIX, CDIM, CDIM);
}